// Round 2
// baseline (496.614 us; speedup 1.0000x reference)
//
#include <hip/hip_runtime.h>
#include <hip/hip_bf16.h>
#include <math.h>

#define BATCH 8
#define KK 19
#define CC 512
#define HW 16384
#define HW4 (HW/4)

// ---------------- Kernel 1: row softmax ----------------
// One workgroup (256 thr) per (b,k) row of 16384 floats.
// Row held in registers (16 float4 / thread). Writes normalized attn to ws.
__global__ __launch_bounds__(256) void softmax_rows(const float* __restrict__ probs,
                                                    float* __restrict__ attn) {
    const int row = blockIdx.x;                       // 0..151  (= b*19 + k)
    const float4* p = (const float4*)(probs + (size_t)row * HW);
    float4* a = (float4*)(attn + (size_t)row * HW);
    const int t = threadIdx.x;

    float4 v[16];
    float m = -INFINITY;
#pragma unroll
    for (int i = 0; i < 16; ++i) {
        v[i] = p[i * 256 + t];
        m = fmaxf(m, fmaxf(fmaxf(v[i].x, v[i].y), fmaxf(v[i].z, v[i].w)));
    }
    // wave (64-lane) max reduce
#pragma unroll
    for (int off = 32; off; off >>= 1) m = fmaxf(m, __shfl_xor(m, off));

    __shared__ float redmax[4];
    __shared__ float redsum[4];
    if ((t & 63) == 0) redmax[t >> 6] = m;
    __syncthreads();
    const float rowmax = fmaxf(fmaxf(redmax[0], redmax[1]), fmaxf(redmax[2], redmax[3]));

    float s = 0.f;
#pragma unroll
    for (int i = 0; i < 16; ++i) {
        v[i].x = __expf(v[i].x - rowmax);
        v[i].y = __expf(v[i].y - rowmax);
        v[i].z = __expf(v[i].z - rowmax);
        v[i].w = __expf(v[i].w - rowmax);
        s += (v[i].x + v[i].y) + (v[i].z + v[i].w);
    }
#pragma unroll
    for (int off = 32; off; off >>= 1) s += __shfl_xor(s, off);
    if ((t & 63) == 0) redsum[t >> 6] = s;
    __syncthreads();
    const float rs = 1.0f / (redsum[0] + redsum[1] + redsum[2] + redsum[3]);

#pragma unroll
    for (int i = 0; i < 16; ++i) {
        float4 o;
        o.x = v[i].x * rs; o.y = v[i].y * rs; o.z = v[i].z * rs; o.w = v[i].w * rs;
        a[i * 256 + t] = o;
    }
}

// ---------------- Kernel 2: ctx[k,c] = sum_n attn[k,n] * feats[c,n] ----------------
// Grid: (C/4 = 128, B = 8). 256 thr = 4 waves; each wave owns one n-quarter
// of the SAME 4 feats rows. Per-thread acc[19][4]; attn float4 reused across
// 4 c's in-register (keeps attn L2 traffic at 19/4 x feats bytes).
__global__ __launch_bounds__(256, 4) void ctx_kernel(const float* __restrict__ feats,
                                                     const float* __restrict__ attn,
                                                     float* __restrict__ out) {
    const int cblk = blockIdx.x;          // 0..127
    const int b    = blockIdx.y;          // 0..7
    const int t    = threadIdx.x;
    const int wave = t >> 6;              // n-quarter index
    const int lane = t & 63;
    const int c0 = cblk * 4;

    const float4* f = (const float4*)(feats + ((size_t)b * CC + c0) * HW);
    const float4* a = (const float4*)(attn + (size_t)b * KK * HW);

    float acc[KK][4];
#pragma unroll
    for (int k = 0; k < KK; ++k)
#pragma unroll
        for (int ci = 0; ci < 4; ++ci) acc[k][ci] = 0.f;

    const int nq0 = wave * (HW4 / 4) + lane;   // float4 index within row

#pragma unroll 1
    for (int it = 0; it < 16; ++it) {
        const int nq = nq0 + it * 64;
        // issue the 4 feats loads first — independent, 16B each
        float4 fv[4];
#pragma unroll
        for (int ci = 0; ci < 4; ++ci) fv[ci] = f[(size_t)ci * HW4 + nq];
        // then stream the 19 attn loads, FMA'ing as they arrive
#pragma unroll
        for (int k = 0; k < KK; ++k) {
            const float4 av = a[(size_t)k * HW4 + nq];
#pragma unroll
            for (int ci = 0; ci < 4; ++ci) {
                acc[k][ci] += av.x * fv[ci].x + av.y * fv[ci].y
                            + av.z * fv[ci].z + av.w * fv[ci].w;
            }
        }
    }

    // wave-level reduce of the 76 partial sums
#pragma unroll
    for (int k = 0; k < KK; ++k) {
#pragma unroll
        for (int ci = 0; ci < 4; ++ci) {
            float s = acc[k][ci];
#pragma unroll
            for (int off = 32; off; off >>= 1) s += __shfl_xor(s, off);
            acc[k][ci] = s;   // all lanes hold the wave sum now
        }
    }

    __shared__ float part[4][KK * 4];
    if (lane < KK) {
#pragma unroll
        for (int ci = 0; ci < 4; ++ci) part[wave][lane * 4 + ci] = acc[lane][ci];
    }
    __syncthreads();

    if (t < KK * 4) {
        const float s = part[0][t] + part[1][t] + part[2][t] + part[3][t];
        const int k = t >> 2;       // t = k*4 + ci
        const int ci = t & 3;
        // out shape (B, C, K, 1): index ((b*C + c)*K + k)
        out[((size_t)b * CC + (c0 + ci)) * KK + k] = s;
    }
}

extern "C" void kernel_launch(void* const* d_in, const int* in_sizes, int n_in,
                              void* d_out, int out_size, void* d_ws, size_t ws_size,
                              hipStream_t stream) {
    const float* feats = (const float*)d_in[0];
    const float* probs = (const float*)d_in[1];
    float* out = (float*)d_out;
    float* attn = (float*)d_ws;   // 8*19*16384 floats = ~9.5 MB scratch

    softmax_rows<<<BATCH * KK, 256, 0, stream>>>(probs, attn);
    ctx_kernel<<<dim3(CC / 4, BATCH), 256, 0, stream>>>(feats, attn, out);
}

// Round 3
// 441.845 us; speedup vs baseline: 1.1240x; 1.1240x over previous
//
#include <hip/hip_runtime.h>
#include <hip/hip_bf16.h>
#include <math.h>

#define BATCH 8
#define KK 19
#define CC 512
#define HW 16384
#define HW4 (HW/4)

// ---------------- Kernel 1: row softmax ----------------
// One workgroup (256 thr) per (b,k) row of 16384 floats.
// Row held in registers (16 float4 / thread). Writes normalized attn to ws.
__global__ __launch_bounds__(256) void softmax_rows(const float* __restrict__ probs,
                                                    float* __restrict__ attn) {
    const int row = blockIdx.x;                       // 0..151  (= b*19 + k)
    const float4* p = (const float4*)(probs + (size_t)row * HW);
    float4* a = (float4*)(attn + (size_t)row * HW);
    const int t = threadIdx.x;

    float4 v[16];
    float m = -INFINITY;
#pragma unroll
    for (int i = 0; i < 16; ++i) {
        v[i] = p[i * 256 + t];
        m = fmaxf(m, fmaxf(fmaxf(v[i].x, v[i].y), fmaxf(v[i].z, v[i].w)));
    }
    // wave (64-lane) max reduce
#pragma unroll
    for (int off = 32; off; off >>= 1) m = fmaxf(m, __shfl_xor(m, off));

    __shared__ float redmax[4];
    __shared__ float redsum[4];
    if ((t & 63) == 0) redmax[t >> 6] = m;
    __syncthreads();
    const float rowmax = fmaxf(fmaxf(redmax[0], redmax[1]), fmaxf(redmax[2], redmax[3]));

    float s = 0.f;
#pragma unroll
    for (int i = 0; i < 16; ++i) {
        v[i].x = __expf(v[i].x - rowmax);
        v[i].y = __expf(v[i].y - rowmax);
        v[i].z = __expf(v[i].z - rowmax);
        v[i].w = __expf(v[i].w - rowmax);
        s += (v[i].x + v[i].y) + (v[i].z + v[i].w);
    }
#pragma unroll
    for (int off = 32; off; off >>= 1) s += __shfl_xor(s, off);
    if ((t & 63) == 0) redsum[t >> 6] = s;
    __syncthreads();
    const float rs = 1.0f / (redsum[0] + redsum[1] + redsum[2] + redsum[3]);

#pragma unroll
    for (int i = 0; i < 16; ++i) {
        float4 o;
        o.x = v[i].x * rs; o.y = v[i].y * rs; o.z = v[i].z * rs; o.w = v[i].w * rs;
        a[i * 256 + t] = o;
    }
}

// ---------------- Kernel 2: ctx[k,c] = sum_n attn[k,n] * feats[c,n] ----------------
// Grid: (C/4 = 128, B = 8). 256 thr = 4 waves; each wave owns one n-quarter
// of the SAME 4 feats rows. Per-thread acc[19][4]; attn float4 reused across
// 4 c's in-register (keeps attn L2 traffic at 19/4 x feats bytes).
// NOTE: every access to acc[][] must be compile-time-indexed or the whole
// array goes to scratch (round-2 bug: VGPR=56, 183 MB scratch write-back).
__global__ __launch_bounds__(256, 4) void ctx_kernel(const float* __restrict__ feats,
                                                     const float* __restrict__ attn,
                                                     float* __restrict__ out) {
    const int cblk = blockIdx.x;          // 0..127
    const int b    = blockIdx.y;          // 0..7
    const int t    = threadIdx.x;
    const int wave = t >> 6;              // n-quarter index
    const int lane = t & 63;
    const int c0 = cblk * 4;

    const float4* f = (const float4*)(feats + ((size_t)b * CC + c0) * HW);
    const float4* a = (const float4*)(attn + (size_t)b * KK * HW);

    float acc[KK][4];
#pragma unroll
    for (int k = 0; k < KK; ++k)
#pragma unroll
        for (int ci = 0; ci < 4; ++ci) acc[k][ci] = 0.f;

    const int nq0 = wave * (HW4 / 4) + lane;   // float4 index within row

#pragma unroll 1
    for (int it = 0; it < 16; ++it) {
        const int nq = nq0 + it * 64;
        // issue the 4 feats loads first — independent, 16B each
        float4 fv[4];
#pragma unroll
        for (int ci = 0; ci < 4; ++ci) fv[ci] = f[(size_t)ci * HW4 + nq];
        // then stream the 19 attn loads, FMA'ing as they arrive
#pragma unroll
        for (int k = 0; k < KK; ++k) {
            const float4 av = a[(size_t)k * HW4 + nq];
#pragma unroll
            for (int ci = 0; ci < 4; ++ci) {
                acc[k][ci] += av.x * fv[ci].x + av.y * fv[ci].y
                            + av.z * fv[ci].z + av.w * fv[ci].w;
            }
        }
    }

    // wave-level butterfly reduce: afterwards EVERY lane holds the wave sum
#pragma unroll
    for (int k = 0; k < KK; ++k) {
#pragma unroll
        for (int ci = 0; ci < 4; ++ci) {
            float s = acc[k][ci];
#pragma unroll
            for (int off = 32; off; off >>= 1) s += __shfl_xor(s, off);
            acc[k][ci] = s;
        }
    }

    __shared__ float part[4][KK * 4];
    // lane 0 writes all 76 values with COMPILE-TIME indices (keeps acc in VGPRs)
    if (lane == 0) {
#pragma unroll
        for (int k = 0; k < KK; ++k)
#pragma unroll
            for (int ci = 0; ci < 4; ++ci)
                part[wave][k * 4 + ci] = acc[k][ci];
    }
    __syncthreads();

    if (t < KK * 4) {
        const float s = part[0][t] + part[1][t] + part[2][t] + part[3][t];
        const int k = t >> 2;       // t = k*4 + ci
        const int ci = t & 3;
        // out shape (B, C, K, 1): index ((b*C + c)*K + k)
        out[((size_t)b * CC + (c0 + ci)) * KK + k] = s;
    }
}

extern "C" void kernel_launch(void* const* d_in, const int* in_sizes, int n_in,
                              void* d_out, int out_size, void* d_ws, size_t ws_size,
                              hipStream_t stream) {
    const float* feats = (const float*)d_in[0];
    const float* probs = (const float*)d_in[1];
    float* out = (float*)d_out;
    float* attn = (float*)d_ws;   // 8*19*16384 floats = ~9.5 MB scratch

    softmax_rows<<<BATCH * KK, 256, 0, stream>>>(probs, attn);
    ctx_kernel<<<dim3(CC / 4, BATCH), 256, 0, stream>>>(feats, attn, out);
}